// Round 3
// baseline (985.219 us; speedup 1.0000x reference)
//
#include <hip/hip_runtime.h>
#include <stdint.h>

// Problem constants: B=2, S=2048, D=1024, H=16, Dk=64
// I/O dtype: float32 (per reference). Internal compute: bf16 MFMA, f32 accum.
#define SB 2048
#define DM 1024
#define NHH 16
#define DKK 64

typedef unsigned short u16;
using short8  = __attribute__((ext_vector_type(8))) short;
using short4v = __attribute__((ext_vector_type(4))) short;
using f32x4   = __attribute__((ext_vector_type(4))) float;

__device__ __forceinline__ u16 f2bf(float f) {
    union { float f; unsigned u; } v; v.f = f;
    unsigned u = v.u;
    return (u16)((u + 0x7FFFu + ((u >> 16) & 1u)) >> 16);  // RNE
}

// stage 16 consecutive f32 -> 16 bf16 (both 16B-aligned)
__device__ __forceinline__ void stage16(const float* __restrict__ src, u16* dst) {
    const float4* s4 = (const float4*)src;
#pragma unroll
    for (int t = 0; t < 2; ++t) {
        const float4 a = s4[2 * t], b = s4[2 * t + 1];
        short8 p;
        p[0] = (short)f2bf(a.x); p[1] = (short)f2bf(a.y);
        p[2] = (short)f2bf(a.z); p[3] = (short)f2bf(a.w);
        p[4] = (short)f2bf(b.x); p[5] = (short)f2bf(b.y);
        p[6] = (short)f2bf(b.z); p[7] = (short)f2bf(b.w);
        *(short8*)(dst + 8 * t) = p;
    }
}

// ---------------------------------------------------------------------------
// Fused projection GEMM (q,k,v in one launch via blockIdx.z):
//   Y[m,n] = sum_k X[m,k]*W[n,k] + bias[n]   (NT, M=4096, N=K=1024)
// 128x128 tile, BK=64, 4 waves each computing a 64x64 sub-tile (4x4 MFMA acc).
// z=0: q -> qh (B,H,S,Dk) ; z=1: k -> kh (B,H,S,Dk) ; z=2: v -> vt (B,H,Dk,S)
// ---------------------------------------------------------------------------
__global__ __launch_bounds__(256) void proj3_kernel(
    const float* __restrict__ q, const float* __restrict__ k, const float* __restrict__ v,
    const float* __restrict__ wq, const float* __restrict__ bq,
    const float* __restrict__ wk, const float* __restrict__ bk,
    const float* __restrict__ wv, const float* __restrict__ bv,
    u16* __restrict__ qh, u16* __restrict__ kh, u16* __restrict__ vt)
{
    __shared__ __align__(16) u16 As[128 * 72];
    __shared__ __align__(16) u16 Bs[128 * 72];

    const int z = blockIdx.z;
    const float* X  = (z == 0) ? q  : (z == 1) ? k  : v;
    const float* W  = (z == 0) ? wq : (z == 1) ? wk : wv;
    const float* Bv = (z == 0) ? bq : (z == 1) ? bk : bv;
    u16*         Y  = (z == 0) ? qh : (z == 1) ? kh : vt;
    const int vmode = (z == 2);

    const int tid  = threadIdx.x;
    const int lane = tid & 63, wv_ = tid >> 6;
    const int li = lane & 15, g = lane >> 4;
    const int wr = wv_ >> 1, wc = wv_ & 1;
    const int m0 = blockIdx.y * 128, n0 = blockIdx.x * 128;

    f32x4 acc[4][4] = {};

    const int rs = tid >> 2;          // 0..63
    const int cs = (tid & 3) * 16;    // 0,16,32,48

    for (int k0 = 0; k0 < DM; k0 += 64) {
        stage16(&X[(m0 + rs) * DM + k0 + cs],      &As[rs * 72 + cs]);
        stage16(&X[(m0 + 64 + rs) * DM + k0 + cs], &As[(64 + rs) * 72 + cs]);
        stage16(&W[(n0 + rs) * DM + k0 + cs],      &Bs[rs * 72 + cs]);
        stage16(&W[(n0 + 64 + rs) * DM + k0 + cs], &Bs[(64 + rs) * 72 + cs]);
        __syncthreads();
#pragma unroll
        for (int kk = 0; kk < 2; ++kk) {
            short8 a[4], b[4];
#pragma unroll
            for (int i = 0; i < 4; ++i)
                a[i] = *(const short8*)&As[(wr * 64 + i * 16 + li) * 72 + kk * 32 + g * 8];
#pragma unroll
            for (int j = 0; j < 4; ++j)
                b[j] = *(const short8*)&Bs[(wc * 64 + j * 16 + li) * 72 + kk * 32 + g * 8];
#pragma unroll
            for (int i = 0; i < 4; ++i)
#pragma unroll
                for (int j = 0; j < 4; ++j)
                    acc[i][j] = __builtin_amdgcn_mfma_f32_16x16x32_bf16(a[i], b[j], acc[i][j], 0, 0, 0);
        }
        __syncthreads();
    }

#pragma unroll
    for (int i = 0; i < 4; ++i)
#pragma unroll
        for (int j = 0; j < 4; ++j) {
            const int n = n0 + wc * 64 + j * 16 + li;
            const float bvv = Bv[n];
            const int mbase = m0 + wr * 64 + i * 16 + g * 4;
            const int h = n >> 6, dk = n & 63;
            if (vmode == 0) {
#pragma unroll
                for (int r = 0; r < 4; ++r) {
                    const int m = mbase + r;
                    const int b = m >> 11, s = m & 2047;
                    Y[(((b * NHH + h) * SB) + s) * DKK + dk] = f2bf(acc[i][j][r] + bvv);
                }
            } else {
                const int b = mbase >> 11, s = mbase & 2047;
                short4v pk;
                pk.x = (short)f2bf(acc[i][j][0] + bvv);
                pk.y = (short)f2bf(acc[i][j][1] + bvv);
                pk.z = (short)f2bf(acc[i][j][2] + bvv);
                pk.w = (short)f2bf(acc[i][j][3] + bvv);
                *(short4v*)&Y[(((b * NHH + h) * DKK) + dk) * SB + s] = pk;
            }
        }
}

// ---------------------------------------------------------------------------
// Fused softmax attention + PV, wave-independent version.
// Block = 64 q-rows (4 waves x 16 rows each), each wave walks ALL 2048 keys.
// -> K/V fetched ~once per XCD per head (vs 64x before); no barriers at all.
// Softmax uses fixed reference 0 (shift-invariant; scores O(10), clamp +80;
// L==0 -> uniform fallback). Pass 1 accumulates l (1 exp2/elem, wave-local
// 16-lane reduce). Pass 2 recomputes scores, writes normalized P with
// NON-TEMPORAL stores (don't evict K/V from L2/L3), accumulates O = P.V.
// ---------------------------------------------------------------------------
__global__ __launch_bounds__(256) void attn_pv_kernel(
    const u16* __restrict__ qh, const u16* __restrict__ kh,
    const u16* __restrict__ vt, const int* __restrict__ mask,
    float* __restrict__ attn_out, u16* __restrict__ oh)
{
    // per-wave P staging: 16 rows x 32 keys bf16, row stride 40 shorts (80B,
    // 16B-aligned rows) -> b128 reads stay aligned, conflicts <= 2-way (free).
    __shared__ __align__(16) u16 Ps[4][16 * 40];

    const int tid = threadIdx.x, lane = tid & 63, w = tid >> 6;
    const int li = lane & 15, g = lane >> 4;
    const int bh = blockIdx.y;                 // b*16+h
    const int q0 = blockIdx.x * 64 + w * 16;   // this wave's 16 q-rows
    const int b  = bh >> 4;
    const float sc2 = 0.125f * 1.44269504088896f;   // (1/sqrt(Dk)) * log2(e)

    const u16* __restrict__ qhb = qh + (size_t)bh * SB * DKK;
    const u16* __restrict__ khb = kh + (size_t)bh * SB * DKK;
    const u16* __restrict__ vtb = vt + (size_t)bh * DKK * SB;
    const int* __restrict__ mkb = mask + b * SB;
    float* __restrict__ aob = attn_out + (size_t)bh * SB * SB;

    short8 qa[2];
#pragma unroll
    for (int kk = 0; kk < 2; ++kk)
        qa[kk] = *(const short8*)&qhb[(q0 + li) * DKK + kk * 32 + g * 8];

    float lloc[4] = {0.f, 0.f, 0.f, 0.f};

    // ---- pass 1: lane-local sum of exp2(score) over all 2048 keys ----
#pragma unroll 2
    for (int kt = 0; kt < 128; ++kt) {
        const int key0 = kt * 16;
        const short8 kb0 = *(const short8*)&khb[(key0 + li) * DKK + g * 8];
        const short8 kb1 = *(const short8*)&khb[(key0 + li) * DKK + 32 + g * 8];
        const int mv = mkb[key0 + li];
        f32x4 acc = {};
        acc = __builtin_amdgcn_mfma_f32_16x16x32_bf16(qa[0], kb0, acc, 0, 0, 0);
        acc = __builtin_amdgcn_mfma_f32_16x16x32_bf16(qa[1], kb1, acc, 0, 0, 0);
#pragma unroll
        for (int r = 0; r < 4; ++r) {
            const float s2 = (mv == 0) ? -1.0e9f : fminf(acc[r] * sc2, 80.0f);
            lloc[r] += exp2f(s2);
        }
    }
    // sum across the 16 lanes (li) holding the same q-row (masks 1..8 in-group)
    float Li[4], Pf[4];
#pragma unroll
    for (int r = 0; r < 4; ++r) {
        float l = lloc[r];
#pragma unroll
        for (int xm = 1; xm < 16; xm <<= 1) l += __shfl_xor(l, xm);
        const bool ok = (l > 1e-37f);
        Li[r] = ok ? 1.0f / l : 0.0f;
        Pf[r] = ok ? 0.0f : (1.0f / 2048.0f);   // fully-masked row -> uniform
    }

    // ---- pass 2: recompute, NT-write normalized P, accumulate O = P.V ----
    f32x4 oacc[4] = {};   // [dk-tile jt]

    for (int pt = 0; pt < 64; ++pt) {
        const int pk0 = pt * 32;     // 32 keys this chunk

        // V B-fragments for this 32-key chunk (L2-resident)
        short8 vb[4];
#pragma unroll
        for (int jt = 0; jt < 4; ++jt)
            vb[jt] = *(const short8*)&vtb[(jt * 16 + li) * SB + pk0 + g * 8];

#pragma unroll
        for (int kk2 = 0; kk2 < 2; ++kk2) {
            const int key0 = pk0 + kk2 * 16;
            const short8 kb0 = *(const short8*)&khb[(key0 + li) * DKK + g * 8];
            const short8 kb1 = *(const short8*)&khb[(key0 + li) * DKK + 32 + g * 8];
            const int mv = mkb[key0 + li];
            f32x4 acc = {};
            acc = __builtin_amdgcn_mfma_f32_16x16x32_bf16(qa[0], kb0, acc, 0, 0, 0);
            acc = __builtin_amdgcn_mfma_f32_16x16x32_bf16(qa[1], kb1, acc, 0, 0, 0);
#pragma unroll
            for (int r = 0; r < 4; ++r) {
                const float s2 = (mv == 0) ? -1.0e9f : fminf(acc[r] * sc2, 80.0f);
                const float p = exp2f(s2) * Li[r] + Pf[r];
                const int row = g * 4 + r;        // 0..15 within wave tile
                __builtin_nontemporal_store(p, &aob[(size_t)(q0 + row) * SB + key0 + li]);
                Ps[w][row * 40 + kk2 * 16 + li] = f2bf(p);
            }
        }

        // PV MFMAs: A = P (16q x 32keys) read back transposed from LDS
        // (same-wave LDS: ordered by lgkmcnt, no barrier needed)
        const short8 pa = *(const short8*)&Ps[w][li * 40 + g * 8];
#pragma unroll
        for (int jt = 0; jt < 4; ++jt)
            oacc[jt] = __builtin_amdgcn_mfma_f32_16x16x32_bf16(pa, vb[jt], oacc[jt], 0, 0, 0);
    }

    // ---- write O tile (16 rows x 64 dk) as bf16, wave-local ----
#pragma unroll
    for (int jt = 0; jt < 4; ++jt)
#pragma unroll
        for (int r = 0; r < 4; ++r)
            oh[((size_t)bh * SB + q0 + g * 4 + r) * DKK + jt * 16 + li] = f2bf(oacc[jt][r]);
}

// ---------------------------------------------------------------------------
// Output projection: out[m,n] = sum_k OH[m,k]*Wo[n,k] + bo[n]
// 128x128 tile, BK=64 (= one head). OH bf16 scratch (B,H,S,Dk) gathered on K.
// ---------------------------------------------------------------------------
__global__ __launch_bounds__(256) void oproj_kernel(
    const u16* __restrict__ OH, const float* __restrict__ W,
    const float* __restrict__ Bv, float* __restrict__ Y)
{
    __shared__ __align__(16) u16 As[128 * 72];
    __shared__ __align__(16) u16 Bs[128 * 72];

    const int tid  = threadIdx.x;
    const int lane = tid & 63, wv = tid >> 6;
    const int li = lane & 15, g = lane >> 4;
    const int wr = wv >> 1, wc = wv & 1;
    const int m0 = blockIdx.y * 128, n0 = blockIdx.x * 128;

    f32x4 acc[4][4] = {};
    const int rs = tid >> 2;          // 0..63
    const int cs = (tid & 3) * 16;    // 0,16,32,48
    const int r0 = tid >> 3;          // 0..31
    const int c0 = (tid & 7) * 8;     // 0..56

    for (int k0 = 0; k0 < DM; k0 += 64) {
        const int h = k0 >> 6;
#pragma unroll
        for (int rr = 0; rr < 4; ++rr) {
            const int m = m0 + rr * 32 + r0, bb = m >> 11, s = m & 2047;
            *(short8*)&As[(rr * 32 + r0) * 72 + c0] =
                *(const short8*)&OH[(((bb * NHH + h) * SB) + s) * DKK + c0];
        }
        stage16(&W[(n0 + rs) * DM + k0 + cs],      &Bs[rs * 72 + cs]);
        stage16(&W[(n0 + 64 + rs) * DM + k0 + cs], &Bs[(64 + rs) * 72 + cs]);
        __syncthreads();
#pragma unroll
        for (int kk = 0; kk < 2; ++kk) {
            short8 a[4], bq[4];
#pragma unroll
            for (int i = 0; i < 4; ++i)
                a[i] = *(const short8*)&As[(wr * 64 + i * 16 + li) * 72 + kk * 32 + g * 8];
#pragma unroll
            for (int j = 0; j < 4; ++j)
                bq[j] = *(const short8*)&Bs[(wc * 64 + j * 16 + li) * 72 + kk * 32 + g * 8];
#pragma unroll
            for (int i = 0; i < 4; ++i)
#pragma unroll
                for (int j = 0; j < 4; ++j)
                    acc[i][j] = __builtin_amdgcn_mfma_f32_16x16x32_bf16(a[i], bq[j], acc[i][j], 0, 0, 0);
        }
        __syncthreads();
    }

#pragma unroll
    for (int i = 0; i < 4; ++i)
#pragma unroll
        for (int j = 0; j < 4; ++j) {
            const int n = n0 + wc * 64 + j * 16 + li;
            const float bv = Bv[n];
            const int mbase = m0 + wr * 64 + i * 16 + g * 4;
#pragma unroll
            for (int r = 0; r < 4; ++r)
                Y[(mbase + r) * DM + n] = acc[i][j][r] + bv;
        }
}

// ---------------------------------------------------------------------------
extern "C" void kernel_launch(void* const* d_in, const int* in_sizes, int n_in,
                              void* d_out, int out_size, void* d_ws, size_t ws_size,
                              hipStream_t stream) {
    const float* q    = (const float*)d_in[0];
    const float* k    = (const float*)d_in[1];
    const float* v    = (const float*)d_in[2];
    const int*   mask = (const int*)d_in[3];
    const float* wq   = (const float*)d_in[4];
    const float* bq   = (const float*)d_in[5];
    const float* wk   = (const float*)d_in[6];
    const float* bk   = (const float*)d_in[7];
    const float* wv   = (const float*)d_in[8];
    const float* bv   = (const float*)d_in[9];
    const float* wo   = (const float*)d_in[10];
    const float* bo   = (const float*)d_in[11];

    float* out  = (float*)d_out;             // (B,S,D) = 4,194,304 f32
    float* attn = out + 4194304;             // (B,H,S,S) = 134,217,728 f32

    // bf16 scratch. qh rows are consumed only by the wave that owns them
    // (read at kernel start), and oh writes land on exactly those rows ->
    // safe to alias oh onto the qh slot even with fused attn+PV.
    u16* ws = (u16*)d_ws;
    u16* qh = ws;                            // (B,H,S,Dk)  [0,8MB)
    u16* kh = ws + 1 * 4194304;              // (B,H,S,Dk)  [8,16MB)
    u16* vt = ws + 2 * 4194304;              // (B,H,Dk,S)  [16,24MB)
    u16* oh = ws;                            // reuses qh slot

    dim3 blk(256);
    proj3_kernel<<<dim3(8, 32, 3), blk, 0, stream>>>(q, k, v, wq, bq, wk, bk, wv, bv, qh, kh, vt);
    attn_pv_kernel<<<dim3(32, 32), blk, 0, stream>>>(qh, kh, vt, mask, attn, oh);
    oproj_kernel<<<dim3(8, 32), blk, 0, stream>>>(oh, wo, bo, out);
}

// Round 4
// 917.422 us; speedup vs baseline: 1.0739x; 1.0739x over previous
//
#include <hip/hip_runtime.h>
#include <stdint.h>

// Problem constants: B=2, S=2048, D=1024, H=16, Dk=64
// I/O dtype: float32 (per reference). Internal compute: bf16 MFMA, f32 accum.
#define SB 2048
#define DM 1024
#define NHH 16
#define DKK 64

typedef unsigned short u16;
using short8  = __attribute__((ext_vector_type(8))) short;
using short4v = __attribute__((ext_vector_type(4))) short;
using f32x4   = __attribute__((ext_vector_type(4))) float;

__device__ __forceinline__ u16 f2bf(float f) {
    union { float f; unsigned u; } v; v.f = f;
    unsigned u = v.u;
    return (u16)((u + 0x7FFFu + ((u >> 16) & 1u)) >> 16);  // RNE
}

// stage 16 consecutive f32 -> 16 bf16 (both 16B-aligned)
__device__ __forceinline__ void stage16(const float* __restrict__ src, u16* dst) {
    const float4* s4 = (const float4*)src;
#pragma unroll
    for (int t = 0; t < 2; ++t) {
        const float4 a = s4[2 * t], b = s4[2 * t + 1];
        short8 p;
        p[0] = (short)f2bf(a.x); p[1] = (short)f2bf(a.y);
        p[2] = (short)f2bf(a.z); p[3] = (short)f2bf(a.w);
        p[4] = (short)f2bf(b.x); p[5] = (short)f2bf(b.y);
        p[6] = (short)f2bf(b.z); p[7] = (short)f2bf(b.w);
        *(short8*)(dst + 8 * t) = p;
    }
}

// ---------------------------------------------------------------------------
// Fused projection GEMM (q,k,v in one launch via blockIdx.z):
//   Y[m,n] = sum_k X[m,k]*W[n,k] + bias[n]   (NT, M=4096, N=K=1024)
// 128x128 tile, BK=64, 4 waves each computing a 64x64 sub-tile (4x4 MFMA acc).
// z=0: q -> qh (B,H,S,Dk) ; z=1: k -> kh (B,H,S,Dk) ; z=2: v -> vt (B,H,Dk,S)
// ---------------------------------------------------------------------------
__global__ __launch_bounds__(256) void proj3_kernel(
    const float* __restrict__ q, const float* __restrict__ k, const float* __restrict__ v,
    const float* __restrict__ wq, const float* __restrict__ bq,
    const float* __restrict__ wk, const float* __restrict__ bk,
    const float* __restrict__ wv, const float* __restrict__ bv,
    u16* __restrict__ qh, u16* __restrict__ kh, u16* __restrict__ vt)
{
    __shared__ __align__(16) u16 As[128 * 72];
    __shared__ __align__(16) u16 Bs[128 * 72];

    const int z = blockIdx.z;
    const float* X  = (z == 0) ? q  : (z == 1) ? k  : v;
    const float* W  = (z == 0) ? wq : (z == 1) ? wk : wv;
    const float* Bv = (z == 0) ? bq : (z == 1) ? bk : bv;
    u16*         Y  = (z == 0) ? qh : (z == 1) ? kh : vt;
    const int vmode = (z == 2);

    const int tid  = threadIdx.x;
    const int lane = tid & 63, wv_ = tid >> 6;
    const int li = lane & 15, g = lane >> 4;
    const int wr = wv_ >> 1, wc = wv_ & 1;
    const int m0 = blockIdx.y * 128, n0 = blockIdx.x * 128;

    f32x4 acc[4][4] = {};

    const int rs = tid >> 2;          // 0..63
    const int cs = (tid & 3) * 16;    // 0,16,32,48

    for (int k0 = 0; k0 < DM; k0 += 64) {
        stage16(&X[(m0 + rs) * DM + k0 + cs],      &As[rs * 72 + cs]);
        stage16(&X[(m0 + 64 + rs) * DM + k0 + cs], &As[(64 + rs) * 72 + cs]);
        stage16(&W[(n0 + rs) * DM + k0 + cs],      &Bs[rs * 72 + cs]);
        stage16(&W[(n0 + 64 + rs) * DM + k0 + cs], &Bs[(64 + rs) * 72 + cs]);
        __syncthreads();
#pragma unroll
        for (int kk = 0; kk < 2; ++kk) {
            short8 a[4], b[4];
#pragma unroll
            for (int i = 0; i < 4; ++i)
                a[i] = *(const short8*)&As[(wr * 64 + i * 16 + li) * 72 + kk * 32 + g * 8];
#pragma unroll
            for (int j = 0; j < 4; ++j)
                b[j] = *(const short8*)&Bs[(wc * 64 + j * 16 + li) * 72 + kk * 32 + g * 8];
#pragma unroll
            for (int i = 0; i < 4; ++i)
#pragma unroll
                for (int j = 0; j < 4; ++j)
                    acc[i][j] = __builtin_amdgcn_mfma_f32_16x16x32_bf16(a[i], b[j], acc[i][j], 0, 0, 0);
        }
        __syncthreads();
    }

#pragma unroll
    for (int i = 0; i < 4; ++i)
#pragma unroll
        for (int j = 0; j < 4; ++j) {
            const int n = n0 + wc * 64 + j * 16 + li;
            const float bvv = Bv[n];
            const int mbase = m0 + wr * 64 + i * 16 + g * 4;
            const int h = n >> 6, dk = n & 63;
            if (vmode == 0) {
#pragma unroll
                for (int r = 0; r < 4; ++r) {
                    const int m = mbase + r;
                    const int b = m >> 11, s = m & 2047;
                    Y[(((b * NHH + h) * SB) + s) * DKK + dk] = f2bf(acc[i][j][r] + bvv);
                }
            } else {
                const int b = mbase >> 11, s = mbase & 2047;
                short4v pk;
                pk.x = (short)f2bf(acc[i][j][0] + bvv);
                pk.y = (short)f2bf(acc[i][j][1] + bvv);
                pk.z = (short)f2bf(acc[i][j][2] + bvv);
                pk.w = (short)f2bf(acc[i][j][3] + bvv);
                *(short4v*)&Y[(((b * NHH + h) * DKK) + dk) * SB + s] = pk;
            }
        }
}

// ---------------------------------------------------------------------------
// Fused softmax attention + PV, SWAPPED-OPERAND layout.
// Round-2 geometry (known-good occupancy): block = (b,h) x 32 q-rows, 4 waves,
// wave w owns keys [w*512, w*512+512). 8 blocks/CU -> 32 waves/CU.
// QK^T computed as mfma(K, Q): acc row index = KEY (g*4+r, lane-local
// consecutive), col = q-row (li). Buys: float4 P stores, cvt_pk+b64 LDS
// staging, 2-shuffle L-reduce. Fragment loads identical to mfma(Q,K) form.
// Softmax fixed-reference-0 (shift-invariant; scores O(10), clamp +80;
// L==0 -> uniform fallback). Cross-wave O combine via LDS atomicAdd.
// ---------------------------------------------------------------------------
__global__ __launch_bounds__(256) void attn_pv_kernel(
    const u16* __restrict__ qh, const u16* __restrict__ kh,
    const u16* __restrict__ vt, const int* __restrict__ mask,
    float* __restrict__ attn_out, u16* __restrict__ oh)
{
    // per-wave P staging: 32 rows(q) x 32 keys bf16, row stride 40 shorts
    // (80 B: 16B-aligned rows; row-to-row bank offset 20 -> <=2-way, free).
    __shared__ __align__(16) u16 Ps[4][32 * 40];
    __shared__ float sl[4][32];
    __shared__ __align__(16) float comb[32 * 68];   // O combine, stride 68 f32

    const int tid = threadIdx.x, lane = tid & 63, w = tid >> 6;
    const int li = lane & 15, g = lane >> 4;
    const int bh = blockIdx.y;           // b*16+h
    const int q0 = blockIdx.x * 32;
    const int b  = bh >> 4;
    const float sc2 = 0.125f * 1.44269504088896f;   // (1/sqrt(Dk)) * log2(e)

    const u16* __restrict__ qhb = qh + (size_t)bh * SB * DKK;
    const u16* __restrict__ khb = kh + (size_t)bh * SB * DKK;
    const u16* __restrict__ vtb = vt + (size_t)bh * DKK * SB;
    const int* __restrict__ mkb = mask + b * SB;
    float* __restrict__ aob = attn_out + (size_t)bh * SB * SB;

    // Q B-fragments: B[col=li (q-row)][k=g*8..] = Q[q0+qs*16+li][dk]
    short8 qa[2][2];
#pragma unroll
    for (int qs = 0; qs < 2; ++qs)
#pragma unroll
        for (int kk = 0; kk < 2; ++kk)
            qa[qs][kk] = *(const short8*)&qhb[(q0 + qs * 16 + li) * DKK + kk * 32 + g * 8];

    float lloc[2] = {0.f, 0.f};
    const int kbase = w * 512;

    // ---- pass 1: sum of exp2(score); acc[r] = key (key0+g*4+r), col = q (li)
    for (int kt = 0; kt < 32; ++kt) {
        const int key0 = kbase + kt * 16;
        const short8 kb0 = *(const short8*)&khb[(key0 + li) * DKK + g * 8];
        const short8 kb1 = *(const short8*)&khb[(key0 + li) * DKK + 32 + g * 8];
        const int4 mv = *(const int4*)&mkb[key0 + g * 4];
#pragma unroll
        for (int qs = 0; qs < 2; ++qs) {
            f32x4 acc = {};
            acc = __builtin_amdgcn_mfma_f32_16x16x32_bf16(kb0, qa[qs][0], acc, 0, 0, 0);
            acc = __builtin_amdgcn_mfma_f32_16x16x32_bf16(kb1, qa[qs][1], acc, 0, 0, 0);
#pragma unroll
            for (int r = 0; r < 4; ++r) {
                const float s2 = ((&mv.x)[r] == 0) ? -1.442695e9f : fminf(acc[r] * sc2, 80.0f);
                lloc[qs] += exp2f(s2);
            }
        }
    }
    // keys are split across g-groups only: 2-shuffle reduce gives per-q (li) sum
#pragma unroll
    for (int qs = 0; qs < 2; ++qs) {
        float l = lloc[qs];
        l += __shfl_xor(l, 16);
        l += __shfl_xor(l, 32);
        lloc[qs] = l;
    }
    if (g == 0) { sl[w][li] = lloc[0]; sl[w][16 + li] = lloc[1]; }
    // zero the O-combine buffer before the barrier that publishes sl
    for (int t = tid; t < 32 * 68; t += 256) comb[t] = 0.f;
    __syncthreads();

    float Li[2], Pf[2];
#pragma unroll
    for (int qs = 0; qs < 2; ++qs) {
        const int rr = qs * 16 + li;
        const float L = sl[0][rr] + sl[1][rr] + sl[2][rr] + sl[3][rr];
        const bool ok = (L > 1e-37f);
        Li[qs] = ok ? 1.0f / L : 0.0f;
        Pf[qs] = ok ? 0.0f : (1.0f / 2048.0f);   // fully-masked row -> uniform
    }

    // ---- pass 2: recompute, float4-write normalized P, accumulate O = P.V
    f32x4 oacc[2][4] = {};   // [qs][dk-tile]; D row = q (g*4+r), col = dk (li)

    for (int pt = 0; pt < 16; ++pt) {
        const int pk0 = kbase + pt * 32;     // 32 keys this chunk

        // V B-fragments: B[col=li (dk)][k=g*8.. (key)] (L2-resident)
        short8 vb[4];
#pragma unroll
        for (int jt = 0; jt < 4; ++jt)
            vb[jt] = *(const short8*)&vtb[(jt * 16 + li) * SB + pk0 + g * 8];

#pragma unroll
        for (int t = 0; t < 2; ++t) {
            const int key0 = pk0 + t * 16;
            const short8 kb0 = *(const short8*)&khb[(key0 + li) * DKK + g * 8];
            const short8 kb1 = *(const short8*)&khb[(key0 + li) * DKK + 32 + g * 8];
            const int4 mv = *(const int4*)&mkb[key0 + g * 4];
#pragma unroll
            for (int qs = 0; qs < 2; ++qs) {
                f32x4 acc = {};
                acc = __builtin_amdgcn_mfma_f32_16x16x32_bf16(kb0, qa[qs][0], acc, 0, 0, 0);
                acc = __builtin_amdgcn_mfma_f32_16x16x32_bf16(kb1, qa[qs][1], acc, 0, 0, 0);
                float p[4];
#pragma unroll
                for (int r = 0; r < 4; ++r) {
                    const float s2 = ((&mv.x)[r] == 0) ? -1.442695e9f : fminf(acc[r] * sc2, 80.0f);
                    p[r] = exp2f(s2) * Li[qs] + Pf[qs];
                }
                // 4 consecutive keys of q-row (q0+qs*16+li): one float4 store
                float4 pf4; pf4.x = p[0]; pf4.y = p[1]; pf4.z = p[2]; pf4.w = p[3];
                *(float4*)&aob[(size_t)(q0 + qs * 16 + li) * SB + key0 + g * 4] = pf4;
                // pack to bf16 pairs and stage to LDS row (q) for PV A-frag
                unsigned d0, d1;
                asm("v_cvt_pk_bf16_f32 %0, %1, %2" : "=v"(d0) : "v"(p[0]), "v"(p[1]));
                asm("v_cvt_pk_bf16_f32 %0, %1, %2" : "=v"(d1) : "v"(p[2]), "v"(p[3]));
                uint2 pd; pd.x = d0; pd.y = d1;
                *(uint2*)&Ps[w][(qs * 16 + li) * 40 + t * 16 + g * 4] = pd;
            }
        }

        // PV MFMAs: A = P[row=li (q)][k=g*8.. (key)] read from LDS
        // (same-wave LDS: ordered by lgkmcnt, no barrier needed)
#pragma unroll
        for (int qs = 0; qs < 2; ++qs) {
            const short8 pa = *(const short8*)&Ps[w][(qs * 16 + li) * 40 + g * 8];
#pragma unroll
            for (int jt = 0; jt < 4; ++jt)
                oacc[qs][jt] = __builtin_amdgcn_mfma_f32_16x16x32_bf16(pa, vb[jt], oacc[qs][jt], 0, 0, 0);
        }
    }

    // ---- combine partial O across the 4 waves via LDS atomics ----
#pragma unroll
    for (int qs = 0; qs < 2; ++qs)
#pragma unroll
        for (int jt = 0; jt < 4; ++jt)
#pragma unroll
            for (int r = 0; r < 4; ++r)
                atomicAdd(&comb[(qs * 16 + g * 4 + r) * 68 + jt * 16 + li], oacc[qs][jt][r]);
    __syncthreads();

    // write O head tile (32 rows x 64 dk) as bf16
    {
        const int row = tid >> 3, c0 = (tid & 7) * 8;
        short8 pk;
#pragma unroll
        for (int j = 0; j < 8; ++j) pk[j] = (short)f2bf(comb[row * 68 + c0 + j]);
        *(short8*)&oh[((bh * SB) + q0 + row) * DKK + c0] = pk;
    }
}

// ---------------------------------------------------------------------------
// Output projection: out[m,n] = sum_k OH[m,k]*Wo[n,k] + bo[n]
// 128x128 tile, BK=64 (= one head). OH bf16 scratch (B,H,S,Dk) gathered on K.
// ---------------------------------------------------------------------------
__global__ __launch_bounds__(256) void oproj_kernel(
    const u16* __restrict__ OH, const float* __restrict__ W,
    const float* __restrict__ Bv, float* __restrict__ Y)
{
    __shared__ __align__(16) u16 As[128 * 72];
    __shared__ __align__(16) u16 Bs[128 * 72];

    const int tid  = threadIdx.x;
    const int lane = tid & 63, wv = tid >> 6;
    const int li = lane & 15, g = lane >> 4;
    const int wr = wv >> 1, wc = wv & 1;
    const int m0 = blockIdx.y * 128, n0 = blockIdx.x * 128;

    f32x4 acc[4][4] = {};
    const int rs = tid >> 2;          // 0..63
    const int cs = (tid & 3) * 16;    // 0,16,32,48
    const int r0 = tid >> 3;          // 0..31
    const int c0 = (tid & 7) * 8;     // 0..56

    for (int k0 = 0; k0 < DM; k0 += 64) {
        const int h = k0 >> 6;
#pragma unroll
        for (int rr = 0; rr < 4; ++rr) {
            const int m = m0 + rr * 32 + r0, bb = m >> 11, s = m & 2047;
            *(short8*)&As[(rr * 32 + r0) * 72 + c0] =
                *(const short8*)&OH[(((bb * NHH + h) * SB) + s) * DKK + c0];
        }
        stage16(&W[(n0 + rs) * DM + k0 + cs],      &Bs[rs * 72 + cs]);
        stage16(&W[(n0 + 64 + rs) * DM + k0 + cs], &Bs[(64 + rs) * 72 + cs]);
        __syncthreads();
#pragma unroll
        for (int kk = 0; kk < 2; ++kk) {
            short8 a[4], bq[4];
#pragma unroll
            for (int i = 0; i < 4; ++i)
                a[i] = *(const short8*)&As[(wr * 64 + i * 16 + li) * 72 + kk * 32 + g * 8];
#pragma unroll
            for (int j = 0; j < 4; ++j)
                bq[j] = *(const short8*)&Bs[(wc * 64 + j * 16 + li) * 72 + kk * 32 + g * 8];
#pragma unroll
            for (int i = 0; i < 4; ++i)
#pragma unroll
                for (int j = 0; j < 4; ++j)
                    acc[i][j] = __builtin_amdgcn_mfma_f32_16x16x32_bf16(a[i], bq[j], acc[i][j], 0, 0, 0);
        }
        __syncthreads();
    }

#pragma unroll
    for (int i = 0; i < 4; ++i)
#pragma unroll
        for (int j = 0; j < 4; ++j) {
            const int n = n0 + wc * 64 + j * 16 + li;
            const float bv = Bv[n];
            const int mbase = m0 + wr * 64 + i * 16 + g * 4;
#pragma unroll
            for (int r = 0; r < 4; ++r)
                Y[(mbase + r) * DM + n] = acc[i][j][r] + bv;
        }
}

// ---------------------------------------------------------------------------
extern "C" void kernel_launch(void* const* d_in, const int* in_sizes, int n_in,
                              void* d_out, int out_size, void* d_ws, size_t ws_size,
                              hipStream_t stream) {
    const float* q    = (const float*)d_in[0];
    const float* k    = (const float*)d_in[1];
    const float* v    = (const float*)d_in[2];
    const int*   mask = (const int*)d_in[3];
    const float* wq   = (const float*)d_in[4];
    const float* bq   = (const float*)d_in[5];
    const float* wk   = (const float*)d_in[6];
    const float* bk   = (const float*)d_in[7];
    const float* wv   = (const float*)d_in[8];
    const float* bv   = (const float*)d_in[9];
    const float* wo   = (const float*)d_in[10];
    const float* bo   = (const float*)d_in[11];

    float* out  = (float*)d_out;             // (B,S,D) = 4,194,304 f32
    float* attn = out + 4194304;             // (B,H,S,S) = 134,217,728 f32

    // bf16 scratch. qh rows are consumed only by the block that owns them
    // (read at kernel start), and oh writes land on exactly those rows ->
    // safe to alias oh onto the qh slot even with fused attn+PV.
    u16* ws = (u16*)d_ws;
    u16* qh = ws;                            // (B,H,S,Dk)  [0,8MB)
    u16* kh = ws + 1 * 4194304;              // (B,H,S,Dk)  [8,16MB)
    u16* vt = ws + 2 * 4194304;              // (B,H,Dk,S)  [16,24MB)
    u16* oh = ws;                            // reuses qh slot

    dim3 blk(256);
    proj3_kernel<<<dim3(8, 32, 3), blk, 0, stream>>>(q, k, v, wq, bq, wk, bk, wv, bv, qh, kh, vt);
    attn_pv_kernel<<<dim3(64, 32), blk, 0, stream>>>(qh, kh, vt, mask, attn, oh);
    oproj_kernel<<<dim3(8, 32), blk, 0, stream>>>(oh, wo, bo, out);
}